// Round 3
// baseline (395.344 us; speedup 1.0000x reference)
//
#include <hip/hip_runtime.h>
#include <hip/hip_bf16.h>

#define N_NODES 50000
#define N_EDGES 800000
#define HIDDEN  256
#define N_LAYERS 3
#define N_PAIRS 4096
#define N_LABEL 8192            // 2*N_PAIRS labeled rows
#define NPAD    50176           // 196*256, padded node count for the scan
#define SCAN_BLOCKS (NPAD / 256) // 196
#define WSZ (HIDDEN * HIDDEN)    // 65536 elems per weight matrix

// Column-blocked x0 layout for the XCD-sliced segment sum:
//   x0b[slice][node][32], slice = col>>5. One slice = 3.2 MB < 4 MB XCD L2.
// Row N_NODES is an all-zero SENTINEL row: CSR segments are padded to a
// multiple of 8 with edges pointing at it -> branch-free window-8 seg loop.
#define NROWPAD (N_NODES + 1)
#define SLICE_ELEMS ((size_t)NROWPAD * 32)
#define SEG_CHUNKS ((N_NODES + 63) / 64)   // 782

typedef __bf16 bf16x8 __attribute__((ext_vector_type(8)));
typedef __bf16 bf16x4 __attribute__((ext_vector_type(4)));
typedef float  f32x4  __attribute__((ext_vector_type(4)));
typedef float  f32x2  __attribute__((ext_vector_type(2)));

__device__ __forceinline__ void load_lds16(const void* g, void* l) {
    __builtin_amdgcn_global_load_lds(
        (const __attribute__((address_space(1))) void*)g,
        (__attribute__((address_space(3))) void*)l, 16, 0, 0);
}

// accumulate 8 bf16 (as uint4) into 4 packed f32 pairs: 3 VALU per pair
// (shl, and, v_pk_add_f32) instead of 4 (cvt+add x2).
__device__ __forceinline__ void acc8(const uint4 w, f32x2* a) {
    a[0] += (f32x2){__uint_as_float(w.x << 16), __uint_as_float(w.x & 0xffff0000u)};
    a[1] += (f32x2){__uint_as_float(w.y << 16), __uint_as_float(w.y & 0xffff0000u)};
    a[2] += (f32x2){__uint_as_float(w.z << 16), __uint_as_float(w.z & 0xffff0000u)};
    a[3] += (f32x2){__uint_as_float(w.w << 16), __uint_as_float(w.w & 0xffff0000u)};
}

// ---------------------------------------------------------------------------
// FUSED layer GEMM: one launch does BOTH node linears of a layer, and (R16)
// for layer 0 also the CSR fill as a third z-plane:
//   blockIdx.z==0 : x0[r] = A[r]@Wt0^T (+deg*bD0) + bC0, stores suppressed
//                   on labeled rows (flags[r]!=0)
//   blockIdx.z==1 : x0[idx[r]] = A[idx[r]]@Wt1^T (+deg*bD1) + bC1
//   blockIdx.z==2 : CSR fill (atomic cursor scatter) — 512 edges/block.
//                   Dispatched after z=0/1 so atomic latency + 16x partial-
//                   line writeback hide under MFMA work (fill was a naked
//                   50us latency-bound kernel; VALUBusy 0.4%, HBM 14%).
// Writes are disjoint by construction -> race-free in a single launch.
// Cout written COLUMN-BLOCKED x0b[col>>5][row][col&31] for the sliced seg.
// ---------------------------------------------------------------------------
template <bool DEG_BIAS, bool A_FP32>
__global__ __launch_bounds__(256) void mfma_gemm_fused(
    const void* __restrict__ A_in,
    const __bf16* __restrict__ Wt0, const __bf16* __restrict__ Wt1,
    const float* __restrict__ bD0, const float* __restrict__ bD1,
    const float* __restrict__ bC0, const float* __restrict__ bC1,
    __bf16* __restrict__ Cout,
    const int* __restrict__ idx,     // pos (labeled rows)
    const int* __restrict__ degv,    // true degree per node
    const int* __restrict__ flags,   // 1 = labeled row
    const int* __restrict__ esrc,    // fill plane (l==0 only)
    const int* __restrict__ edst,
    int* __restrict__ cursor,
    int* __restrict__ ssorted,
    int M)
{
    const int role = blockIdx.z;
    if (role == 2) {
        // CSR fill plane: 1564 blocks x 512 edges (1564*512 = 800768)
        const int eb = blockIdx.x * 2 + blockIdx.y;
        int e = eb * 512 + threadIdx.x;
        #pragma unroll
        for (int r = 0; r < 2; ++r) {
            if (e < N_EDGES) {
                const int p = atomicAdd(&cursor[edst[e]], 1);
                ssorted[p] = esrc[e];
            }
            e += 256;
        }
        return;
    }
    if (role == 1 && blockIdx.x >= N_LABEL / 64) return;

    const __bf16* A   = (const __bf16*)A_in;
    const float*  A32 = (const float*)A_in;
    const __bf16* Wt  = role ? Wt1 : Wt0;
    const float*  bD  = role ? bD1 : bD0;
    const float*  bC  = role ? bC1 : bC0;

    __shared__ __bf16 As[64 * 32];    // 4 KB
    __shared__ __bf16 Bs[128 * 32];   // 8 KB
    __shared__ int s_idx[64];

    const int t    = threadIdx.x;
    const int lane = t & 63;
    const int wave = t >> 6;
    const int m0   = blockIdx.x * 64;
    const int n0   = blockIdx.y * 128;

    if (role == 1) {
        if (t < 64) s_idx[t] = idx[m0 + t];
        __syncthreads();
    }

    const int arow  = t >> 2;
    const int acol8 = (t & 3) * 8;
    int anode;
    if (role == 1) {
        anode = s_idx[arow];
    } else {
        const int rg = m0 + arow;
        anode = (rg < M) ? rg : (M - 1);   // clamp; stores guarded below
    }
    const __bf16* aptr   = A   + (size_t)anode * HIDDEN + acol8;
    const float*  aptr32 = A32 + (size_t)anode * HIDDEN + acol8;

    const __bf16* bptr[2];
    #pragma unroll
    for (int r = 0; r < 2; ++r) {
        const int c = r * 256 + t;
        bptr[r] = Wt + (size_t)(n0 + (c >> 2)) * HIDDEN + (c & 3) * 8;
    }

    f32x4 acc[8];
    #pragma unroll
    for (int i = 0; i < 8; ++i) acc[i] = (f32x4){0.f, 0.f, 0.f, 0.f};

    const int wm   = wave * 16;
    const int fm   = lane & 15;
    const int quad = lane >> 4;

    for (int k0 = 0; k0 < HIDDEN; k0 += 32) {
        __syncthreads();
        if constexpr (A_FP32) {
            const float* ap = aptr32 + k0;
            const float4 u0 = *(const float4*)(ap);
            const float4 u1 = *(const float4*)(ap + 4);
            bf16x8 w = {(__bf16)u0.x, (__bf16)u0.y, (__bf16)u0.z, (__bf16)u0.w,
                        (__bf16)u1.x, (__bf16)u1.y, (__bf16)u1.z, (__bf16)u1.w};
            *(bf16x8*)(As + (size_t)t * 8) = w;
        } else {
            load_lds16(aptr + k0, (void*)(As + (size_t)t * 8));
        }
        #pragma unroll
        for (int r = 0; r < 2; ++r)
            load_lds16(bptr[r] + k0, (void*)(Bs + (size_t)(r * 256 + t) * 8));
        __syncthreads();

        const bf16x8 af = *(const bf16x8*)(As + (wm + fm) * 32 + quad * 8);
        bf16x8 bfr[8];
        #pragma unroll
        for (int nt = 0; nt < 8; ++nt)
            bfr[nt] = *(const bf16x8*)(Bs + (nt * 16 + fm) * 32 + quad * 8);

        #pragma unroll
        for (int nt = 0; nt < 8; ++nt)
            acc[nt] = __builtin_amdgcn_mfma_f32_16x16x32_bf16(
                af, bfr[nt], acc[nt], 0, 0, 0);
    }

    // epilogue: C/D layout col=lane&15, row=quad*4+reg (m89/m91-verified)
    float bd[8], bc[8];
    #pragma unroll
    for (int nt = 0; nt < 8; ++nt) {
        const int col = n0 + nt * 16 + fm;
        bd[nt] = DEG_BIAS ? bD[col] : 0.f;
        bc[nt] = bC[col];
    }

    #pragma unroll
    for (int rg = 0; rg < 4; ++rg) {
        const int rloc = wm + quad * 4 + rg;
        int orow;
        if (role == 1) {
            orow = s_idx[rloc];
        } else {
            orow = m0 + rloc;
            if (orow >= M) continue;
            if (flags[orow]) continue;     // labeled: z=1 writes this row
        }
        float bscale = 0.f;
        if constexpr (DEG_BIAS)
            bscale = (float)degv[orow];
        #pragma unroll
        for (int nt = 0; nt < 8; ++nt) {
            const int cb = n0 + nt * 16;       // 16-col group, no 32-boundary cross
            float v = acc[nt][rg];
            if constexpr (DEG_BIAS) v += bscale * bd[nt];
            v += bc[nt];
            // column-blocked store: x0b[cb>>5][orow][ (cb&31)+fm ]
            Cout[(size_t)(cb >> 5) * SLICE_ELEMS + (size_t)orow * 32
                 + (cb & 31) + fm] = (__bf16)v;
        }
    }
}

// ---------------------------------------------------------------------------
// Plain MFMA GEMM (product batch + final out GEMM).  64x128 tile.
//   GATHER_A   : A-rows gathered via idx (A indexed by node id)
//   DEG_VIA_IDX: A sequential/compact but deg looked up via idx[rloc]
// Row-major in/out (NOT blocked) — only the fused GEMM feeds the seg-sum.
// ---------------------------------------------------------------------------
template <bool GATHER_A, bool DEG_BIAS, bool DEG_VIA_IDX, bool OUT_BF16, bool PROD_BATCH>
__global__ __launch_bounds__(256) void mfma_gemm(
    const __bf16* __restrict__ A_in,
    const __bf16* __restrict__ Wt_in,
    const float* __restrict__ biasD,
    void* __restrict__ Cout_in,
    const int* __restrict__ idx,
    const int* __restrict__ degv,
    int M)
{
    const __bf16* A  = A_in;
    const __bf16* Wt = Wt_in;
    void* Cout = Cout_in;
    if constexpr (PROD_BATCH) {
        const int z = blockIdx.z;
        A    = A_in  + (size_t)(3 * (1 + (z >> 1)) + (z & 1)) * WSZ;
        Wt   = Wt_in + (size_t)(z >> 1) * WSZ;
        Cout = (void*)((__bf16*)Cout_in + (size_t)z * WSZ);
    }

    __shared__ __bf16 As[64 * 32];
    __shared__ __bf16 Bs[128 * 32];
    __shared__ int s_idx[64];

    const int t    = threadIdx.x;
    const int lane = t & 63;
    const int wave = t >> 6;
    const int m0   = blockIdx.x * 64;
    const int n0   = blockIdx.y * 128;

    if constexpr (GATHER_A || DEG_VIA_IDX) {
        if (t < 64) s_idx[t] = idx[m0 + t];
        __syncthreads();
    }

    const int arow  = t >> 2;
    const int acol8 = (t & 3) * 8;
    int anode;
    if constexpr (GATHER_A) {
        anode = s_idx[arow];
    } else {
        const int rg = m0 + arow;
        anode = (rg < M) ? rg : (M - 1);
    }
    const __bf16* aptr = A + (size_t)anode * HIDDEN + acol8;

    const __bf16* bptr[2];
    #pragma unroll
    for (int r = 0; r < 2; ++r) {
        const int c = r * 256 + t;
        bptr[r] = Wt + (size_t)(n0 + (c >> 2)) * HIDDEN + (c & 3) * 8;
    }

    f32x4 acc[8];
    #pragma unroll
    for (int i = 0; i < 8; ++i) acc[i] = (f32x4){0.f, 0.f, 0.f, 0.f};

    const int wm   = wave * 16;
    const int fm   = lane & 15;
    const int quad = lane >> 4;

    for (int k0 = 0; k0 < HIDDEN; k0 += 32) {
        __syncthreads();
        load_lds16(aptr + k0, (void*)(As + (size_t)t * 8));
        #pragma unroll
        for (int r = 0; r < 2; ++r)
            load_lds16(bptr[r] + k0, (void*)(Bs + (size_t)(r * 256 + t) * 8));
        __syncthreads();

        const bf16x8 af = *(const bf16x8*)(As + (wm + fm) * 32 + quad * 8);
        bf16x8 bfr[8];
        #pragma unroll
        for (int nt = 0; nt < 8; ++nt)
            bfr[nt] = *(const bf16x8*)(Bs + (nt * 16 + fm) * 32 + quad * 8);

        #pragma unroll
        for (int nt = 0; nt < 8; ++nt)
            acc[nt] = __builtin_amdgcn_mfma_f32_16x16x32_bf16(
                af, bfr[nt], acc[nt], 0, 0, 0);
    }

    float bd[8];
    #pragma unroll
    for (int nt = 0; nt < 8; ++nt)
        bd[nt] = DEG_BIAS ? biasD[n0 + nt * 16 + fm] : 0.f;

    #pragma unroll
    for (int rg = 0; rg < 4; ++rg) {
        const int rloc = wm + quad * 4 + rg;
        const int orow = m0 + rloc;
        if (!PROD_BATCH && orow >= M) continue;
        int dnode = orow;
        if constexpr (GATHER_A || DEG_VIA_IDX) dnode = s_idx[rloc];
        float bscale = 0.f;
        if constexpr (DEG_BIAS)
            bscale = (float)degv[dnode];
        #pragma unroll
        for (int nt = 0; nt < 8; ++nt) {
            const int col = n0 + nt * 16 + fm;
            float v = acc[nt][rg];
            if constexpr (DEG_BIAS) v += bscale * bd[nt];
            if constexpr (OUT_BF16)
                ((__bf16*)Cout)[(size_t)orow * HIDDEN + col] = (__bf16)v;
            else
                ((float*)Cout)[(size_t)orow * HIDDEN + col] = v;
        }
    }
}

// ---------------------------------------------------------------------------
// Weight prep + edge histogram, one launch, 61 z-slices:
//  z 0..8 : T[z][n][k] = (bf16)W_z[k][n]   (transpose; z = layer*3 + which)
//  z 9..10: cw_nt[z-9] = (bf16)conv_w[z-9] (straight convert)
//  z 11   : qprod — blocks (x<4, y==0): q[x][n] = sum_k cb_l[k]*W[k][n]
//  z 12..60: edge histogram + labeled flags + x0b sentinel-row zeroing
//            (3136 blocks x 256 edges; hides the 800K no-return atomics
//             under the weight transposes instead of a naked ~25us kernel)
// ---------------------------------------------------------------------------
__global__ __launch_bounds__(256) void wconv_kernel(
    const float* __restrict__ f0_w, const float* __restrict__ f1_w,
    const float* __restrict__ conv_w, const float* __restrict__ conv_b,
    __bf16* __restrict__ wt_all, __bf16* __restrict__ cw_nt,
    float* __restrict__ q,
    const int* __restrict__ edge_dst, const int* __restrict__ pos,
    int* __restrict__ counts, int* __restrict__ flags,
    __bf16* __restrict__ x0b)
{
    const int z = blockIdx.z;
    const int tx = threadIdx.x, ty = threadIdx.y;

    if (z >= 12) {
        const int plane = z - 12;
        const int t = ty * 32 + tx;
        const int eb = plane * 64 + blockIdx.x * 8 + blockIdx.y;
        const int e = eb * 256 + t;
        if (e < N_EDGES) atomicAdd(&counts[edge_dst[e]], 1);
        if (e < N_LABEL) flags[pos[e]] = 1;   // benign dup writes
        if (plane == 0 && blockIdx.x == 0 && blockIdx.y == 0) {
            // zero the sentinel row (node N_NODES) in each of the 8 slices
            const int sl = t >> 5, c = t & 31;
            x0b[(size_t)sl * SLICE_ELEMS + (size_t)N_NODES * 32 + c] = (__bf16)0.f;
        }
        return;
    }

    const int kx = blockIdx.x * 32, nx = blockIdx.y * 32;

    if (z < 9) {
        const int layer = z / 3, which = z % 3;
        const float* W = ((which == 0) ? f0_w : (which == 1) ? f1_w : conv_w)
                         + (size_t)layer * WSZ;
        __bf16* T = wt_all + (size_t)z * WSZ;

        __shared__ float tile[32][33];
        for (int i = ty; i < 32; i += 8)
            tile[i][tx] = W[(size_t)(kx + i) * HIDDEN + nx + tx];
        __syncthreads();
        for (int i = ty; i < 32; i += 8)
            T[(size_t)(nx + i) * HIDDEN + kx + tx] = (__bf16)tile[tx][i];
    } else if (z < 11) {
        const int layer = z - 9;
        const float* W = conv_w + (size_t)layer * WSZ;
        __bf16* T = cw_nt + (size_t)layer * WSZ;
        for (int i = ty; i < 32; i += 8)
            T[(size_t)(kx + i) * HIDDEN + nx + tx] =
                (__bf16)W[(size_t)(kx + i) * HIDDEN + nx + tx];
    } else {
        // qprod: 4 active blocks (x<4, y==0), 256 threads each
        if (blockIdx.x >= 4 || blockIdx.y != 0) return;
        const int zq = blockIdx.x;
        const int l = zq >> 1, branch = zq & 1;
        const float* cb = conv_b + (size_t)l * HIDDEN;
        const float* W  = (branch ? f1_w : f0_w) + (size_t)(l + 1) * WSZ;
        const int n = ty * 32 + tx;
        float s = 0.f;
        #pragma unroll 4
        for (int k = 0; k < HIDDEN; ++k)
            s += cb[k] * W[(size_t)k * HIDDEN + n];
        q[(size_t)zq * HIDDEN + n] = s;
    }
}

__device__ __forceinline__ int block_incl_scan(int v, int* s, int t)
{
    s[t] = v; __syncthreads();
    #pragma unroll
    for (int off = 1; off < 256; off <<= 1) {
        int add = (t >= off) ? s[t - off] : 0;
        __syncthreads();
        s[t] += add;
        __syncthreads();
    }
    return s[t];
}

__global__ __launch_bounds__(256) void scan1_kernel(
    const int* __restrict__ counts, int* __restrict__ offs, int* __restrict__ bsum)
{
    __shared__ int s[256];
    const int t = threadIdx.x;
    const int i = blockIdx.x * 256 + t;
    const int pv = (counts[i] + 7) & ~7;       // padded segment length
    int incl = block_incl_scan(pv, s, t);
    offs[i] = incl - pv;
    if (t == 255) bsum[blockIdx.x] = incl;
}

__global__ __launch_bounds__(256) void scan2_kernel(
    const int* __restrict__ bsum, int* __restrict__ bbase)
{
    __shared__ int s[256];
    const int t = threadIdx.x;
    const int v = (t < SCAN_BLOCKS) ? bsum[t] : 0;
    int incl = block_incl_scan(v, s, t);
    bbase[t] = incl - v;
}

__global__ __launch_bounds__(256) void scan3_kernel(
    int* __restrict__ offs, const int* __restrict__ bbase,
    int* __restrict__ cursor, const int* __restrict__ counts,
    int* __restrict__ src_sorted)
{
    const int i = blockIdx.x * 256 + threadIdx.x;
    const int o = offs[i] + bbase[blockIdx.x];
    offs[i] = o;
    cursor[i] = o;
    // fill the padding tail of this segment with the zero-row sentinel
    const int v  = counts[i];
    const int pv = (v + 7) & ~7;
    for (int j = o + v; j < o + pv; ++j) src_sorted[j] = N_NODES;
}

// ---------------------------------------------------------------------------
// XCD-sliced pull-mode segment sum, branch-free window-8 (R15).
// Segments are PADDED to a multiple of 8 with sentinel (zero-row) edges:
//   - indices loaded directly as aligned int4 pairs (no shfl broadcast)
//   - no per-element predication, no tail loop
//   - gathers via uniform base + 32-bit voffset (s-base addressing)
//   - accumulate as packed f32 pairs (v_pk_add_f32 path)
// slice = blockIdx.x & 7 pins each 3.2MB column slice to one XCD L2.
// ---------------------------------------------------------------------------
template <bool COMPACT>
__global__ __launch_bounds__(256) void seg_slice_kernel(
    const __bf16* __restrict__ x0b,
    const int* __restrict__ srcs,
    const int* __restrict__ offs,      // PADDED offsets (multiples of 8)
    const int* __restrict__ nodelist,
    __bf16* __restrict__ out)
{
    const int slice = blockIdx.x & 7;
    const int chunk = blockIdx.x >> 3;
    const int t    = threadIdx.x;
    const int wave = t >> 6;
    const int lane = t & 63;
    const int g    = lane >> 2;      // 16 groups per wave
    const int li   = lane & 3;       // 4 lanes per dst row, 8 cols each
    const int rw   = chunk * 64 + wave * 16 + g;
    if (!COMPACT && rw >= N_NODES) return;

    const int d    = COMPACT ? nodelist[rw] : rw;
    const int beg  = offs[d];
    const int pdeg = offs[d + 1] - beg;   // multiple of 8

    const char* xb = (const char*)(x0b + (size_t)slice * SLICE_ELEMS);
    const uint32_t lioff = (uint32_t)li * 16u;
    const int* sp = srcs + beg;           // 32B-aligned

    f32x2 a[4];
    #pragma unroll
    for (int j = 0; j < 4; ++j) a[j] = (f32x2){0.f, 0.f};

    int4 j0, j1;
    if (pdeg > 0) {
        j0 = *(const int4*)(sp);
        j1 = *(const int4*)(sp + 4);
    }

    for (int base = 0; base < pdeg; base += 8) {
        const int4 k0 = j0, k1 = j1;
        if (base + 8 < pdeg) {            // prefetch next window's indices
            j0 = *(const int4*)(sp + base + 8);
            j1 = *(const int4*)(sp + base + 12);
        }
        const uint4 c0 = *(const uint4*)(xb + (((uint32_t)k0.x << 6) + lioff));
        const uint4 c1 = *(const uint4*)(xb + (((uint32_t)k0.y << 6) + lioff));
        const uint4 c2 = *(const uint4*)(xb + (((uint32_t)k0.z << 6) + lioff));
        const uint4 c3 = *(const uint4*)(xb + (((uint32_t)k0.w << 6) + lioff));
        const uint4 c4 = *(const uint4*)(xb + (((uint32_t)k1.x << 6) + lioff));
        const uint4 c5 = *(const uint4*)(xb + (((uint32_t)k1.y << 6) + lioff));
        const uint4 c6 = *(const uint4*)(xb + (((uint32_t)k1.z << 6) + lioff));
        const uint4 c7 = *(const uint4*)(xb + (((uint32_t)k1.w << 6) + lioff));
        acc8(c0, a); acc8(c1, a); acc8(c2, a); acc8(c3, a);
        acc8(c4, a); acc8(c5, a); acc8(c6, a); acc8(c7, a);
    }

    bf16x8 o;
    #pragma unroll
    for (int j = 0; j < 4; ++j) {
        o[2 * j]     = (__bf16)a[j].x;
        o[2 * j + 1] = (__bf16)a[j].y;
    }
    *(bf16x8*)(out + (size_t)rw * HIDDEN + (slice << 5) + li * 8) = o;
}

extern "C" void kernel_launch(void* const* d_in, const int* in_sizes, int n_in,
                              void* d_out, int out_size, void* d_ws, size_t ws_size,
                              hipStream_t stream)
{
    const float* x       = (const float*)d_in[0];
    const float* f0_w    = (const float*)d_in[1];
    const float* f0_b    = (const float*)d_in[2];
    const float* f1_w    = (const float*)d_in[3];
    const float* f1_b    = (const float*)d_in[4];
    const float* conv_w  = (const float*)d_in[5];
    const float* conv_b  = (const float*)d_in[6];
    const int*   edge_src = (const int*)d_in[7];
    const int*   edge_dst = (const int*)d_in[8];
    const int*   pos      = (const int*)d_in[9];
    float* out = (float*)d_out;

    const size_t buf = (size_t)N_NODES * HIDDEN;   // 12.8M elems

    char* p = (char*)d_ws;
    __bf16* bufA   = (__bf16*)p; p += buf * 2;                 // 25.6 MB (row-major S)
    __bf16* bufB   = (__bf16*)p; p += SLICE_ELEMS * 8 * 2;     // 25.6 MB+ (blocked x0 + sentinel)
    __bf16* s_lbl  = (__bf16*)p; p += (size_t)N_LABEL * HIDDEN * 2;  // 4 MB
    __bf16* wt_all = (__bf16*)p; p += (size_t)9 * WSZ * 2;
    __bf16* prod   = (__bf16*)p; p += (size_t)4 * WSZ * 2;
    __bf16* cw_nt  = (__bf16*)p; p += (size_t)2 * WSZ * 2;
    float*  qv     = (float*)p;  p += (size_t)4 * HIDDEN * 4;
    int* counts     = (int*)p;  p += NPAD * 4;     // true degree (kept live!)
    int* flags      = (int*)p;  p += NPAD * 4;     // labeled-row bitmap
    int* offs       = (int*)p;  p += NPAD * 4;     // PADDED offsets
    int* cursor     = (int*)p;  p += NPAD * 4;
    int* bsum       = (int*)p;  p += 256 * 4;
    int* bbase      = (int*)p;  p += 256 * 4;
    int* src_sorted = (int*)p;  p += (size_t)(N_EDGES + 7 * NPAD) * 4;

    // ---- CSR build stage 1: histogram+flags fused into weight prep ----
    hipMemsetAsync(counts, 0, 2 * NPAD * sizeof(int), stream);
    wconv_kernel<<<dim3(8, 8, 61), dim3(32, 8), 0, stream>>>(
        f0_w, f1_w, conv_w, conv_b, wt_all, cw_nt, qv,
        edge_dst, pos, counts, flags, bufB);
    scan1_kernel<<<SCAN_BLOCKS, 256, 0, stream>>>(counts, offs, bsum);
    scan2_kernel<<<1, 256, 0, stream>>>(bsum, bbase);
    scan3_kernel<<<SCAN_BLOCKS, 256, 0, stream>>>(offs, bbase, cursor, counts, src_sorted);

    // all 4 products prod_t[z] = (Cw_l · F_{l+1})^T in ONE batched launch
    mfma_gemm<false, false, false, true, true><<<dim3(4, 2, 4), 256, 0, stream>>>(
        wt_all, cw_nt, nullptr, prod, nullptr, nullptr, HIDDEN);

    const dim3 fused_grid0(782, 2, 3);  // z=0 full, z=1 label, z=2 CSR fill
    const dim3 fused_grid(782, 2, 2);   // z=0 full, z=1 label
    const dim3 lbl_grid(128, 2);

    __bf16* cur = bufA;              // S buffer (layer-0 GEMMs read x fp32)
    __bf16* tmp = bufB;              // x0 buffer, COLUMN-BLOCKED layout

    for (int l = 0; l < N_LAYERS; ++l) {
        const float* B0 = f0_b + (size_t)l * HIDDEN;
        const float* B1 = f1_b + (size_t)l * HIDDEN;

        if (l == 0) {
            // x0 = x@F0_0+b0 (all, minus labeled) ∪ x@F1_0+b1 (labeled)
            // + z=2 plane: CSR fill overlapped with the GEMM
            mfma_gemm_fused<false, true><<<fused_grid0, 256, 0, stream>>>(
                x, wt_all + 0 * WSZ, wt_all + 1 * WSZ,
                nullptr, nullptr, B0, B1, tmp, pos, counts, flags,
                edge_src, edge_dst, cursor, src_sorted, N_NODES);
        } else {
            // x0 = S@(Cw·F0_l)+deg*q0+b0 ∪ S@(Cw·F1_l)+deg*q1+b1 (folded conv)
            const int z0 = (l - 1) * 2;
            mfma_gemm_fused<true, false><<<fused_grid, 256, 0, stream>>>(
                cur, prod + (size_t)z0 * WSZ, prod + (size_t)(z0 + 1) * WSZ,
                qv + (size_t)z0 * HIDDEN, qv + (size_t)(z0 + 1) * HIDDEN,
                B0, B1, tmp, pos, counts, flags,
                nullptr, nullptr, nullptr, nullptr, N_NODES);
        }

        if (l < N_LAYERS - 1) {
            // S = segment_sum(x0[src]) at ALL nodes (tmp -> cur), XCD-sliced
            seg_slice_kernel<false><<<8 * SEG_CHUNKS, 256, 0, stream>>>(
                tmp, src_sorted, offs, nullptr, cur);
        } else {
            // S only at labeled dst nodes (tmp -> s_lbl, compact pos order)
            seg_slice_kernel<true><<<8 * (N_LABEL / 64), 256, 0, stream>>>(
                tmp, src_sorted, offs, pos, s_lbl);
            // out[i] = S_lbl[i] @ Cw_2 + deg[pos[i]]*cb_2  -> d_out (fp32)
            mfma_gemm<false, true, true, false, false><<<lbl_grid, 256, 0, stream>>>(
                s_lbl, wt_all + (size_t)(2 * 3 + 2) * WSZ,
                conv_b + (size_t)2 * HIDDEN, out, pos, counts, N_LABEL);
        }
    }
}

// Round 4
// 384.324 us; speedup vs baseline: 1.0287x; 1.0287x over previous
//
#include <hip/hip_runtime.h>
#include <hip/hip_bf16.h>

#define N_NODES 50000
#define N_EDGES 800000
#define HIDDEN  256
#define N_LAYERS 3
#define N_PAIRS 4096
#define N_LABEL 8192            // 2*N_PAIRS labeled rows
#define NPAD    50176           // 196*256, padded node count for the scan
#define SCAN_BLOCKS (NPAD / 256) // 196
#define WSZ (HIDDEN * HIDDEN)    // 65536 elems per weight matrix

// Column-blocked x0 layout for the XCD-sliced segment sum:
//   x0b[slice][node][32], slice = col>>5. One slice = 3.2 MB < 4 MB XCD L2.
// Row N_NODES is an all-zero SENTINEL row: CSR segments are padded to a
// multiple of 8 with edges pointing at it -> branch-free window-8 seg loop.
#define NROWPAD (N_NODES + 1)
#define SLICE_ELEMS ((size_t)NROWPAD * 32)
#define SEG_CHUNKS ((N_NODES + 63) / 64)   // 782

// R17 interleaved-fill flat grid for the layer-0 fused GEMM:
//   ids 0..3135: groups of 8 alternate {gemm0, fill} -> both roles spread
//   across all 8 XCDs (id%8 round-robin) AND co-resident in time.
//   ids 3136..3391: label role (256 blocks).
#define G0_PAIRS   3136                    // 196 groups of 16 (8 gemm + 8 fill)
#define G0_TOTAL   (G0_PAIRS + 256)        // 3392

typedef __bf16 bf16x8 __attribute__((ext_vector_type(8)));
typedef __bf16 bf16x4 __attribute__((ext_vector_type(4)));
typedef float  f32x4  __attribute__((ext_vector_type(4)));
typedef float  f32x2  __attribute__((ext_vector_type(2)));

__device__ __forceinline__ void load_lds16(const void* g, void* l) {
    __builtin_amdgcn_global_load_lds(
        (const __attribute__((address_space(1))) void*)g,
        (__attribute__((address_space(3))) void*)l, 16, 0, 0);
}

// accumulate 8 bf16 (as uint4) into 4 packed f32 pairs: 3 VALU per pair
// (shl, and, v_pk_add_f32) instead of 4 (cvt+add x2).
__device__ __forceinline__ void acc8(const uint4 w, f32x2* a) {
    a[0] += (f32x2){__uint_as_float(w.x << 16), __uint_as_float(w.x & 0xffff0000u)};
    a[1] += (f32x2){__uint_as_float(w.y << 16), __uint_as_float(w.y & 0xffff0000u)};
    a[2] += (f32x2){__uint_as_float(w.z << 16), __uint_as_float(w.z & 0xffff0000u)};
    a[3] += (f32x2){__uint_as_float(w.w << 16), __uint_as_float(w.w & 0xffff0000u)};
}

// ---------------------------------------------------------------------------
// FUSED layer GEMM: one launch does BOTH node linears of a layer.
// FILL_PLANE (layer 0 only): flat 1D grid interleaves CSR-fill blocks with
// GEMM blocks in groups of 8 (see G0_* above) so the 800K atomic-scatter's
// latency hides under MFMA + HBM streaming (R16's z-plane variant dispatched
// fill last -> zero overlap, 93us ~= serial sum; counters: MfmaUtil 3%,
// hbm 1.5 TB/s -> latency-bound tail).
//   role 0 : x0[r] = A[r]@Wt0^T (+deg*bD0) + bC0, stores suppressed on
//            labeled rows (flags[r]!=0)
//   role 1 : x0[idx[r]] = A[idx[r]]@Wt1^T (+deg*bD1) + bC1
//   fill   : p = atomicAdd(cursor[dst[e]]); src_sorted[p] = src[e]
// Writes are disjoint by construction -> race-free in a single launch.
// Cout written COLUMN-BLOCKED x0b[col>>5][row][col&31] for the sliced seg.
// ---------------------------------------------------------------------------
template <bool DEG_BIAS, bool A_FP32, bool FILL_PLANE>
__global__ __launch_bounds__(256) void mfma_gemm_fused(
    const void* __restrict__ A_in,
    const __bf16* __restrict__ Wt0, const __bf16* __restrict__ Wt1,
    const float* __restrict__ bD0, const float* __restrict__ bD1,
    const float* __restrict__ bC0, const float* __restrict__ bC1,
    __bf16* __restrict__ Cout,
    const int* __restrict__ idx,     // pos (labeled rows)
    const int* __restrict__ degv,    // true degree per node
    const int* __restrict__ flags,   // 1 = labeled row
    const int* __restrict__ esrc,    // fill plane (l==0 only)
    const int* __restrict__ edst,
    int* __restrict__ cursor,
    int* __restrict__ ssorted,
    int M)
{
    int role, bx, by;
    if constexpr (FILL_PLANE) {
        const int id = blockIdx.x;
        if (id < G0_PAIRS) {
            const int sub = ((id >> 4) << 3) | (id & 7);   // 0..1567
            if ((id >> 3) & 1) {
                // ---- CSR fill block: 512 edges, 2 independent chains ----
                int e = sub * 512 + (int)threadIdx.x;
                #pragma unroll
                for (int r = 0; r < 2; ++r) {
                    if (e < N_EDGES) {
                        const int p = atomicAdd(&cursor[edst[e]], 1);
                        ssorted[p] = esrc[e];
                    }
                    e += 256;
                }
                return;
            }
            role = 0; bx = sub >> 1; by = sub & 1;
            if (bx >= 782) return;
        } else {
            const int lb = id - G0_PAIRS;    // 0..255
            role = 1; bx = lb & 127; by = lb >> 7;
        }
    } else {
        role = blockIdx.z; bx = blockIdx.x; by = blockIdx.y;
        if (role == 1 && bx >= N_LABEL / 64) return;
    }

    const __bf16* A   = (const __bf16*)A_in;
    const float*  A32 = (const float*)A_in;
    const __bf16* Wt  = role ? Wt1 : Wt0;
    const float*  bD  = role ? bD1 : bD0;
    const float*  bC  = role ? bC1 : bC0;

    __shared__ __bf16 As[64 * 32];    // 4 KB
    __shared__ __bf16 Bs[128 * 32];   // 8 KB
    __shared__ int s_idx[64];

    const int t    = threadIdx.x;
    const int lane = t & 63;
    const int wave = t >> 6;
    const int m0   = bx * 64;
    const int n0   = by * 128;

    if (role == 1) {
        if (t < 64) s_idx[t] = idx[m0 + t];
        __syncthreads();
    }

    const int arow  = t >> 2;
    const int acol8 = (t & 3) * 8;
    int anode;
    if (role == 1) {
        anode = s_idx[arow];
    } else {
        const int rg = m0 + arow;
        anode = (rg < M) ? rg : (M - 1);   // clamp; stores guarded below
    }
    const __bf16* aptr   = A   + (size_t)anode * HIDDEN + acol8;
    const float*  aptr32 = A32 + (size_t)anode * HIDDEN + acol8;

    const __bf16* bptr[2];
    #pragma unroll
    for (int r = 0; r < 2; ++r) {
        const int c = r * 256 + t;
        bptr[r] = Wt + (size_t)(n0 + (c >> 2)) * HIDDEN + (c & 3) * 8;
    }

    f32x4 acc[8];
    #pragma unroll
    for (int i = 0; i < 8; ++i) acc[i] = (f32x4){0.f, 0.f, 0.f, 0.f};

    const int wm   = wave * 16;
    const int fm   = lane & 15;
    const int quad = lane >> 4;

    for (int k0 = 0; k0 < HIDDEN; k0 += 32) {
        __syncthreads();
        if constexpr (A_FP32) {
            const float* ap = aptr32 + k0;
            const float4 u0 = *(const float4*)(ap);
            const float4 u1 = *(const float4*)(ap + 4);
            bf16x8 w = {(__bf16)u0.x, (__bf16)u0.y, (__bf16)u0.z, (__bf16)u0.w,
                        (__bf16)u1.x, (__bf16)u1.y, (__bf16)u1.z, (__bf16)u1.w};
            *(bf16x8*)(As + (size_t)t * 8) = w;
        } else {
            load_lds16(aptr + k0, (void*)(As + (size_t)t * 8));
        }
        #pragma unroll
        for (int r = 0; r < 2; ++r)
            load_lds16(bptr[r] + k0, (void*)(Bs + (size_t)(r * 256 + t) * 8));
        __syncthreads();

        const bf16x8 af = *(const bf16x8*)(As + (wm + fm) * 32 + quad * 8);
        bf16x8 bfr[8];
        #pragma unroll
        for (int nt = 0; nt < 8; ++nt)
            bfr[nt] = *(const bf16x8*)(Bs + (nt * 16 + fm) * 32 + quad * 8);

        #pragma unroll
        for (int nt = 0; nt < 8; ++nt)
            acc[nt] = __builtin_amdgcn_mfma_f32_16x16x32_bf16(
                af, bfr[nt], acc[nt], 0, 0, 0);
    }

    // epilogue: C/D layout col=lane&15, row=quad*4+reg (m89/m91-verified)
    float bd[8], bc[8];
    #pragma unroll
    for (int nt = 0; nt < 8; ++nt) {
        const int col = n0 + nt * 16 + fm;
        bd[nt] = DEG_BIAS ? bD[col] : 0.f;
        bc[nt] = bC[col];
    }

    #pragma unroll
    for (int rg = 0; rg < 4; ++rg) {
        const int rloc = wm + quad * 4 + rg;
        int orow;
        if (role == 1) {
            orow = s_idx[rloc];
        } else {
            orow = m0 + rloc;
            if (orow >= M) continue;
            if (flags[orow]) continue;     // labeled: z=1 writes this row
        }
        float bscale = 0.f;
        if constexpr (DEG_BIAS)
            bscale = (float)degv[orow];
        #pragma unroll
        for (int nt = 0; nt < 8; ++nt) {
            const int cb = n0 + nt * 16;       // 16-col group, no 32-boundary cross
            float v = acc[nt][rg];
            if constexpr (DEG_BIAS) v += bscale * bd[nt];
            v += bc[nt];
            // column-blocked store: x0b[cb>>5][orow][ (cb&31)+fm ]
            Cout[(size_t)(cb >> 5) * SLICE_ELEMS + (size_t)orow * 32
                 + (cb & 31) + fm] = (__bf16)v;
        }
    }
}

// ---------------------------------------------------------------------------
// Plain MFMA GEMM (product batch + final out GEMM).  64x128 tile.
//   GATHER_A   : A-rows gathered via idx (A indexed by node id)
//   DEG_VIA_IDX: A sequential/compact but deg looked up via idx[rloc]
// Row-major in/out (NOT blocked) — only the fused GEMM feeds the seg-sum.
// ---------------------------------------------------------------------------
template <bool GATHER_A, bool DEG_BIAS, bool DEG_VIA_IDX, bool OUT_BF16, bool PROD_BATCH>
__global__ __launch_bounds__(256) void mfma_gemm(
    const __bf16* __restrict__ A_in,
    const __bf16* __restrict__ Wt_in,
    const float* __restrict__ biasD,
    void* __restrict__ Cout_in,
    const int* __restrict__ idx,
    const int* __restrict__ degv,
    int M)
{
    const __bf16* A  = A_in;
    const __bf16* Wt = Wt_in;
    void* Cout = Cout_in;
    if constexpr (PROD_BATCH) {
        const int z = blockIdx.z;
        A    = A_in  + (size_t)(3 * (1 + (z >> 1)) + (z & 1)) * WSZ;
        Wt   = Wt_in + (size_t)(z >> 1) * WSZ;
        Cout = (void*)((__bf16*)Cout_in + (size_t)z * WSZ);
    }

    __shared__ __bf16 As[64 * 32];
    __shared__ __bf16 Bs[128 * 32];
    __shared__ int s_idx[64];

    const int t    = threadIdx.x;
    const int lane = t & 63;
    const int wave = t >> 6;
    const int m0   = blockIdx.x * 64;
    const int n0   = blockIdx.y * 128;

    if constexpr (GATHER_A || DEG_VIA_IDX) {
        if (t < 64) s_idx[t] = idx[m0 + t];
        __syncthreads();
    }

    const int arow  = t >> 2;
    const int acol8 = (t & 3) * 8;
    int anode;
    if constexpr (GATHER_A) {
        anode = s_idx[arow];
    } else {
        const int rg = m0 + arow;
        anode = (rg < M) ? rg : (M - 1);
    }
    const __bf16* aptr = A + (size_t)anode * HIDDEN + acol8;

    const __bf16* bptr[2];
    #pragma unroll
    for (int r = 0; r < 2; ++r) {
        const int c = r * 256 + t;
        bptr[r] = Wt + (size_t)(n0 + (c >> 2)) * HIDDEN + (c & 3) * 8;
    }

    f32x4 acc[8];
    #pragma unroll
    for (int i = 0; i < 8; ++i) acc[i] = (f32x4){0.f, 0.f, 0.f, 0.f};

    const int wm   = wave * 16;
    const int fm   = lane & 15;
    const int quad = lane >> 4;

    for (int k0 = 0; k0 < HIDDEN; k0 += 32) {
        __syncthreads();
        load_lds16(aptr + k0, (void*)(As + (size_t)t * 8));
        #pragma unroll
        for (int r = 0; r < 2; ++r)
            load_lds16(bptr[r] + k0, (void*)(Bs + (size_t)(r * 256 + t) * 8));
        __syncthreads();

        const bf16x8 af = *(const bf16x8*)(As + (wm + fm) * 32 + quad * 8);
        bf16x8 bfr[8];
        #pragma unroll
        for (int nt = 0; nt < 8; ++nt)
            bfr[nt] = *(const bf16x8*)(Bs + (nt * 16 + fm) * 32 + quad * 8);

        #pragma unroll
        for (int nt = 0; nt < 8; ++nt)
            acc[nt] = __builtin_amdgcn_mfma_f32_16x16x32_bf16(
                af, bfr[nt], acc[nt], 0, 0, 0);
    }

    float bd[8];
    #pragma unroll
    for (int nt = 0; nt < 8; ++nt)
        bd[nt] = DEG_BIAS ? biasD[n0 + nt * 16 + fm] : 0.f;

    #pragma unroll
    for (int rg = 0; rg < 4; ++rg) {
        const int rloc = wm + quad * 4 + rg;
        const int orow = m0 + rloc;
        if (!PROD_BATCH && orow >= M) continue;
        int dnode = orow;
        if constexpr (GATHER_A || DEG_VIA_IDX) dnode = s_idx[rloc];
        float bscale = 0.f;
        if constexpr (DEG_BIAS)
            bscale = (float)degv[dnode];
        #pragma unroll
        for (int nt = 0; nt < 8; ++nt) {
            const int col = n0 + nt * 16 + fm;
            float v = acc[nt][rg];
            if constexpr (DEG_BIAS) v += bscale * bd[nt];
            if constexpr (OUT_BF16)
                ((__bf16*)Cout)[(size_t)orow * HIDDEN + col] = (__bf16)v;
            else
                ((float*)Cout)[(size_t)orow * HIDDEN + col] = v;
        }
    }
}

// ---------------------------------------------------------------------------
// Weight prep + edge histogram, one launch, 61 z-slices:
//  z 0..8 : T[z][n][k] = (bf16)W_z[k][n]   (transpose; z = layer*3 + which)
//  z 9..10: cw_nt[z-9] = (bf16)conv_w[z-9] (straight convert)
//  z 11   : qprod — blocks (x<4, y==0): q[x][n] = sum_k cb_l[k]*W[k][n]
//  z 12..60: edge histogram + labeled flags + x0b sentinel-row zeroing
// ---------------------------------------------------------------------------
__global__ __launch_bounds__(256) void wconv_kernel(
    const float* __restrict__ f0_w, const float* __restrict__ f1_w,
    const float* __restrict__ conv_w, const float* __restrict__ conv_b,
    __bf16* __restrict__ wt_all, __bf16* __restrict__ cw_nt,
    float* __restrict__ q,
    const int* __restrict__ edge_dst, const int* __restrict__ pos,
    int* __restrict__ counts, int* __restrict__ flags,
    __bf16* __restrict__ x0b)
{
    const int z = blockIdx.z;
    const int tx = threadIdx.x, ty = threadIdx.y;

    if (z >= 12) {
        const int plane = z - 12;
        const int t = ty * 32 + tx;
        const int eb = plane * 64 + blockIdx.x * 8 + blockIdx.y;
        const int e = eb * 256 + t;
        if (e < N_EDGES) atomicAdd(&counts[edge_dst[e]], 1);
        if (e < N_LABEL) flags[pos[e]] = 1;   // benign dup writes
        if (plane == 0 && blockIdx.x == 0 && blockIdx.y == 0) {
            // zero the sentinel row (node N_NODES) in each of the 8 slices
            const int sl = t >> 5, c = t & 31;
            x0b[(size_t)sl * SLICE_ELEMS + (size_t)N_NODES * 32 + c] = (__bf16)0.f;
        }
        return;
    }

    const int kx = blockIdx.x * 32, nx = blockIdx.y * 32;

    if (z < 9) {
        const int layer = z / 3, which = z % 3;
        const float* W = ((which == 0) ? f0_w : (which == 1) ? f1_w : conv_w)
                         + (size_t)layer * WSZ;
        __bf16* T = wt_all + (size_t)z * WSZ;

        __shared__ float tile[32][33];
        for (int i = ty; i < 32; i += 8)
            tile[i][tx] = W[(size_t)(kx + i) * HIDDEN + nx + tx];
        __syncthreads();
        for (int i = ty; i < 32; i += 8)
            T[(size_t)(nx + i) * HIDDEN + kx + tx] = (__bf16)tile[tx][i];
    } else if (z < 11) {
        const int layer = z - 9;
        const float* W = conv_w + (size_t)layer * WSZ;
        __bf16* T = cw_nt + (size_t)layer * WSZ;
        for (int i = ty; i < 32; i += 8)
            T[(size_t)(kx + i) * HIDDEN + nx + tx] =
                (__bf16)W[(size_t)(kx + i) * HIDDEN + nx + tx];
    } else {
        // qprod: 4 active blocks (x<4, y==0), 256 threads each
        if (blockIdx.x >= 4 || blockIdx.y != 0) return;
        const int zq = blockIdx.x;
        const int l = zq >> 1, branch = zq & 1;
        const float* cb = conv_b + (size_t)l * HIDDEN;
        const float* W  = (branch ? f1_w : f0_w) + (size_t)(l + 1) * WSZ;
        const int n = ty * 32 + tx;
        float s = 0.f;
        #pragma unroll 4
        for (int k = 0; k < HIDDEN; ++k)
            s += cb[k] * W[(size_t)k * HIDDEN + n];
        q[(size_t)zq * HIDDEN + n] = s;
    }
}

__device__ __forceinline__ int block_incl_scan(int v, int* s, int t)
{
    s[t] = v; __syncthreads();
    #pragma unroll
    for (int off = 1; off < 256; off <<= 1) {
        int add = (t >= off) ? s[t - off] : 0;
        __syncthreads();
        s[t] += add;
        __syncthreads();
    }
    return s[t];
}

__global__ __launch_bounds__(256) void scan1_kernel(
    const int* __restrict__ counts, int* __restrict__ offs, int* __restrict__ bsum)
{
    __shared__ int s[256];
    const int t = threadIdx.x;
    const int i = blockIdx.x * 256 + t;
    const int pv = (counts[i] + 7) & ~7;       // padded segment length
    int incl = block_incl_scan(pv, s, t);
    offs[i] = incl - pv;
    if (t == 255) bsum[blockIdx.x] = incl;
}

__global__ __launch_bounds__(256) void scan2_kernel(
    const int* __restrict__ bsum, int* __restrict__ bbase)
{
    __shared__ int s[256];
    const int t = threadIdx.x;
    const int v = (t < SCAN_BLOCKS) ? bsum[t] : 0;
    int incl = block_incl_scan(v, s, t);
    bbase[t] = incl - v;
}

__global__ __launch_bounds__(256) void scan3_kernel(
    int* __restrict__ offs, const int* __restrict__ bbase,
    int* __restrict__ cursor, const int* __restrict__ counts,
    int* __restrict__ src_sorted)
{
    const int i = blockIdx.x * 256 + threadIdx.x;
    const int o = offs[i] + bbase[blockIdx.x];
    offs[i] = o;
    cursor[i] = o;
    // fill the padding tail of this segment with the zero-row sentinel
    const int v  = counts[i];
    const int pv = (v + 7) & ~7;
    for (int j = o + v; j < o + pv; ++j) src_sorted[j] = N_NODES;
}

// ---------------------------------------------------------------------------
// XCD-sliced pull-mode segment sum, branch-free window-8 (R15).
// Segments are PADDED to a multiple of 8 with sentinel (zero-row) edges:
//   - indices loaded directly as aligned int4 pairs (no shfl broadcast)
//   - no per-element predication, no tail loop
//   - gathers via uniform base + 32-bit voffset (s-base addressing)
//   - accumulate as packed f32 pairs (v_pk_add_f32 path)
// slice = blockIdx.x & 7 pins each 3.2MB column slice to one XCD L2.
// ---------------------------------------------------------------------------
template <bool COMPACT>
__global__ __launch_bounds__(256) void seg_slice_kernel(
    const __bf16* __restrict__ x0b,
    const int* __restrict__ srcs,
    const int* __restrict__ offs,      // PADDED offsets (multiples of 8)
    const int* __restrict__ nodelist,
    __bf16* __restrict__ out)
{
    const int slice = blockIdx.x & 7;
    const int chunk = blockIdx.x >> 3;
    const int t    = threadIdx.x;
    const int wave = t >> 6;
    const int lane = t & 63;
    const int g    = lane >> 2;      // 16 groups per wave
    const int li   = lane & 3;       // 4 lanes per dst row, 8 cols each
    const int rw   = chunk * 64 + wave * 16 + g;
    if (!COMPACT && rw >= N_NODES) return;

    const int d    = COMPACT ? nodelist[rw] : rw;
    const int beg  = offs[d];
    const int pdeg = offs[d + 1] - beg;   // multiple of 8

    const char* xb = (const char*)(x0b + (size_t)slice * SLICE_ELEMS);
    const uint32_t lioff = (uint32_t)li * 16u;
    const int* sp = srcs + beg;           // 32B-aligned

    f32x2 a[4];
    #pragma unroll
    for (int j = 0; j < 4; ++j) a[j] = (f32x2){0.f, 0.f};

    int4 j0, j1;
    if (pdeg > 0) {
        j0 = *(const int4*)(sp);
        j1 = *(const int4*)(sp + 4);
    }

    for (int base = 0; base < pdeg; base += 8) {
        const int4 k0 = j0, k1 = j1;
        if (base + 8 < pdeg) {            // prefetch next window's indices
            j0 = *(const int4*)(sp + base + 8);
            j1 = *(const int4*)(sp + base + 12);
        }
        const uint4 c0 = *(const uint4*)(xb + (((uint32_t)k0.x << 6) + lioff));
        const uint4 c1 = *(const uint4*)(xb + (((uint32_t)k0.y << 6) + lioff));
        const uint4 c2 = *(const uint4*)(xb + (((uint32_t)k0.z << 6) + lioff));
        const uint4 c3 = *(const uint4*)(xb + (((uint32_t)k0.w << 6) + lioff));
        const uint4 c4 = *(const uint4*)(xb + (((uint32_t)k1.x << 6) + lioff));
        const uint4 c5 = *(const uint4*)(xb + (((uint32_t)k1.y << 6) + lioff));
        const uint4 c6 = *(const uint4*)(xb + (((uint32_t)k1.z << 6) + lioff));
        const uint4 c7 = *(const uint4*)(xb + (((uint32_t)k1.w << 6) + lioff));
        acc8(c0, a); acc8(c1, a); acc8(c2, a); acc8(c3, a);
        acc8(c4, a); acc8(c5, a); acc8(c6, a); acc8(c7, a);
    }

    bf16x8 o;
    #pragma unroll
    for (int j = 0; j < 4; ++j) {
        o[2 * j]     = (__bf16)a[j].x;
        o[2 * j + 1] = (__bf16)a[j].y;
    }
    *(bf16x8*)(out + (size_t)rw * HIDDEN + (slice << 5) + li * 8) = o;
}

extern "C" void kernel_launch(void* const* d_in, const int* in_sizes, int n_in,
                              void* d_out, int out_size, void* d_ws, size_t ws_size,
                              hipStream_t stream)
{
    const float* x       = (const float*)d_in[0];
    const float* f0_w    = (const float*)d_in[1];
    const float* f0_b    = (const float*)d_in[2];
    const float* f1_w    = (const float*)d_in[3];
    const float* f1_b    = (const float*)d_in[4];
    const float* conv_w  = (const float*)d_in[5];
    const float* conv_b  = (const float*)d_in[6];
    const int*   edge_src = (const int*)d_in[7];
    const int*   edge_dst = (const int*)d_in[8];
    const int*   pos      = (const int*)d_in[9];
    float* out = (float*)d_out;

    const size_t buf = (size_t)N_NODES * HIDDEN;   // 12.8M elems

    char* p = (char*)d_ws;
    __bf16* bufA   = (__bf16*)p; p += buf * 2;                 // 25.6 MB (row-major S)
    __bf16* bufB   = (__bf16*)p; p += SLICE_ELEMS * 8 * 2;     // 25.6 MB+ (blocked x0 + sentinel)
    __bf16* s_lbl  = (__bf16*)p; p += (size_t)N_LABEL * HIDDEN * 2;  // 4 MB
    __bf16* wt_all = (__bf16*)p; p += (size_t)9 * WSZ * 2;
    __bf16* prod   = (__bf16*)p; p += (size_t)4 * WSZ * 2;
    __bf16* cw_nt  = (__bf16*)p; p += (size_t)2 * WSZ * 2;
    float*  qv     = (float*)p;  p += (size_t)4 * HIDDEN * 4;
    int* counts     = (int*)p;  p += NPAD * 4;     // true degree (kept live!)
    int* flags      = (int*)p;  p += NPAD * 4;     // labeled-row bitmap
    int* offs       = (int*)p;  p += NPAD * 4;     // PADDED offsets
    int* cursor     = (int*)p;  p += NPAD * 4;
    int* bsum       = (int*)p;  p += 256 * 4;
    int* bbase      = (int*)p;  p += 256 * 4;
    int* src_sorted = (int*)p;  p += (size_t)(N_EDGES + 7 * NPAD) * 4;

    // ---- CSR build stage 1: histogram+flags fused into weight prep ----
    hipMemsetAsync(counts, 0, 2 * NPAD * sizeof(int), stream);
    wconv_kernel<<<dim3(8, 8, 61), dim3(32, 8), 0, stream>>>(
        f0_w, f1_w, conv_w, conv_b, wt_all, cw_nt, qv,
        edge_dst, pos, counts, flags, bufB);
    scan1_kernel<<<SCAN_BLOCKS, 256, 0, stream>>>(counts, offs, bsum);
    scan2_kernel<<<1, 256, 0, stream>>>(bsum, bbase);
    scan3_kernel<<<SCAN_BLOCKS, 256, 0, stream>>>(offs, bbase, cursor, counts, src_sorted);

    // all 4 products prod_t[z] = (Cw_l · F_{l+1})^T in ONE batched launch
    mfma_gemm<false, false, false, true, true><<<dim3(4, 2, 4), 256, 0, stream>>>(
        wt_all, cw_nt, nullptr, prod, nullptr, nullptr, HIDDEN);

    const dim3 fused_grid(782, 2, 2);   // z=0 full, z=1 label (layers 1..)
    const dim3 lbl_grid(128, 2);

    __bf16* cur = bufA;              // S buffer (layer-0 GEMMs read x fp32)
    __bf16* tmp = bufB;              // x0 buffer, COLUMN-BLOCKED layout

    for (int l = 0; l < N_LAYERS; ++l) {
        const float* B0 = f0_b + (size_t)l * HIDDEN;
        const float* B1 = f1_b + (size_t)l * HIDDEN;

        if (l == 0) {
            // x0 = x@F0_0+b0 (all, minus labeled) ∪ x@F1_0+b1 (labeled)
            // + CSR fill blocks INTERLEAVED in groups of 8 (flat 1D grid)
            mfma_gemm_fused<false, true, true><<<G0_TOTAL, 256, 0, stream>>>(
                x, wt_all + 0 * WSZ, wt_all + 1 * WSZ,
                nullptr, nullptr, B0, B1, tmp, pos, counts, flags,
                edge_src, edge_dst, cursor, src_sorted, N_NODES);
        } else {
            // x0 = S@(Cw·F0_l)+deg*q0+b0 ∪ S@(Cw·F1_l)+deg*q1+b1 (folded conv)
            const int z0 = (l - 1) * 2;
            mfma_gemm_fused<true, false, false><<<fused_grid, 256, 0, stream>>>(
                cur, prod + (size_t)z0 * WSZ, prod + (size_t)(z0 + 1) * WSZ,
                qv + (size_t)z0 * HIDDEN, qv + (size_t)(z0 + 1) * HIDDEN,
                B0, B1, tmp, pos, counts, flags,
                nullptr, nullptr, nullptr, nullptr, N_NODES);
        }

        if (l < N_LAYERS - 1) {
            // S = segment_sum(x0[src]) at ALL nodes (tmp -> cur), XCD-sliced
            seg_slice_kernel<false><<<8 * SEG_CHUNKS, 256, 0, stream>>>(
                tmp, src_sorted, offs, nullptr, cur);
        } else {
            // S only at labeled dst nodes (tmp -> s_lbl, compact pos order)
            seg_slice_kernel<true><<<8 * (N_LABEL / 64), 256, 0, stream>>>(
                tmp, src_sorted, offs, pos, s_lbl);
            // out[i] = S_lbl[i] @ Cw_2 + deg[pos[i]]*cb_2  -> d_out (fp32)
            mfma_gemm<false, true, true, false, false><<<lbl_grid, 256, 0, stream>>>(
                s_lbl, wt_all + (size_t)(2 * 3 + 2) * WSZ,
                conv_b + (size_t)2 * HIDDEN, out, pos, counts, N_LABEL);
        }
    }
}

// Round 5
// 355.213 us; speedup vs baseline: 1.1130x; 1.0820x over previous
//
#include <hip/hip_runtime.h>
#include <hip/hip_bf16.h>

#define N_NODES 50000
#define N_EDGES 800000
#define HIDDEN  256
#define N_LAYERS 3
#define N_PAIRS 4096
#define N_LABEL 8192            // 2*N_PAIRS labeled rows
#define NPAD    50176           // 196*256, padded node count for the scan
#define SCAN_BLOCKS (NPAD / 256) // 196
#define WSZ (HIDDEN * HIDDEN)    // 65536 elems per weight matrix
#define NSTEP (HIDDEN / 32)      // 8 K-steps

// Column-blocked x0 layout for the XCD-sliced segment sum:
//   x0b[slice][node][32], slice = col>>5. One slice = 3.2 MB < 4 MB XCD L2.
// Row N_NODES is an all-zero SENTINEL row: CSR segments are padded to a
// multiple of 8 with edges pointing at it -> branch-free window-8 seg loop.
#define NROWPAD (N_NODES + 1)
#define SLICE_ELEMS ((size_t)NROWPAD * 32)
#define SEG_CHUNKS ((N_NODES + 63) / 64)   // 782

// Interleaved-fill flat grid for the layer-0 fused GEMM (R17):
//   ids 0..3135: groups of 8 alternate {gemm0, fill} -> both roles spread
//   across all 8 XCDs (id%8 round-robin) AND co-resident in time.
//   ids 3136..3391: label role (256 blocks).
#define G0_PAIRS   3136
#define G0_TOTAL   (G0_PAIRS + 256)

typedef __bf16 bf16x8 __attribute__((ext_vector_type(8)));
typedef float  f32x4  __attribute__((ext_vector_type(4)));
typedef float  f32x2  __attribute__((ext_vector_type(2)));

__device__ __forceinline__ void load_lds16(const void* g, void* l) {
    __builtin_amdgcn_global_load_lds(
        (const __attribute__((address_space(1))) void*)g,
        (__attribute__((address_space(3))) void*)l, 16, 0, 0);
}

// accumulate 8 bf16 (as uint4) into 4 packed f32 pairs (v_pk_add_f32 path)
__device__ __forceinline__ void acc8(const uint4 w, f32x2* a) {
    a[0] += (f32x2){__uint_as_float(w.x << 16), __uint_as_float(w.x & 0xffff0000u)};
    a[1] += (f32x2){__uint_as_float(w.y << 16), __uint_as_float(w.y & 0xffff0000u)};
    a[2] += (f32x2){__uint_as_float(w.z << 16), __uint_as_float(w.z & 0xffff0000u)};
    a[3] += (f32x2){__uint_as_float(w.w << 16), __uint_as_float(w.w & 0xffff0000u)};
}

// ---------------------------------------------------------------------------
// R18 GEMM K-loop: depth-2 prefetch, 3 LDS buffers, counted vmcnt + raw
// s_barrier (guide T3/T4, m201-verified pattern). Old structure was
// sync->stage->sync(vmcnt0)->compute: per K-step serial ~900cy latency,
// MfmaUtil 3.5%, ~4x off roofline. Now stage(t+2) issues before compute(t);
// vmcnt(3) lets the newest stage's 3 loads stay in flight across the
// barrier, so each stage has ~2 compute phases to land -> stall ~0.
// Every stage is EXACTLY 3 global_load_lds (A x1, B x2) -> vmcnt arithmetic
// uniform (x pre-converted to bf16; no fp32 path).
// ---------------------------------------------------------------------------
#define GEMM_PIPELINE(APTR, BPTR, AS, BS)                                     \
    {                                                                          \
        load_lds16((APTR), (void*)((AS) + (size_t)t * 8));                     \
        load_lds16((BPTR)[0], (void*)((BS) + (size_t)t * 8));                  \
        load_lds16((BPTR)[1], (void*)((BS) + (size_t)(256 + t) * 8));          \
    }

// ---------------------------------------------------------------------------
// FUSED layer GEMM: one launch does BOTH node linears of a layer.
// FILL_PLANE (layer 0): flat 1D grid interleaves atomic-free CSR-fill blocks
// with GEMM blocks in groups of 8 (R17). Fill uses precomputed rank[e]
// (returned by hist's atomicAdd) -> no atomic round-trip, pure scatter.
//   role 0 : x0[r] = A[r]@Wt0^T (+deg*bD0) + bC0, stores suppressed on
//            labeled rows (flags[r]!=0)
//   role 1 : x0[idx[r]] = A[idx[r]]@Wt1^T (+deg*bD1) + bC1
//   fill   : ssorted[offs[dst[e]] + rank[e]] = src[e]
// Writes disjoint by construction -> race-free in a single launch.
// Cout written COLUMN-BLOCKED x0b[col>>5][row][col&31] for the sliced seg.
// ---------------------------------------------------------------------------
template <bool DEG_BIAS, bool FILL_PLANE>
__global__ __launch_bounds__(256) void mfma_gemm_fused(
    const __bf16* __restrict__ A,
    const __bf16* __restrict__ Wt0, const __bf16* __restrict__ Wt1,
    const float* __restrict__ bD0, const float* __restrict__ bD1,
    const float* __restrict__ bC0, const float* __restrict__ bC1,
    __bf16* __restrict__ Cout,
    const int* __restrict__ idx,     // pos (labeled rows)
    const int* __restrict__ degv,    // true degree per node
    const int* __restrict__ flags,   // 1 = labeled row
    const int* __restrict__ esrc,    // fill (l==0 only)
    const int* __restrict__ edst,
    const int* __restrict__ coffs,   // padded offsets (fill)
    const int* __restrict__ rankv,   // per-edge rank from hist
    int* __restrict__ ssorted,
    int M)
{
    int role, bx, by;
    if constexpr (FILL_PLANE) {
        const int id = blockIdx.x;
        if (id < G0_PAIRS) {
            const int sub = ((id >> 4) << 3) | (id & 7);   // 0..1567
            if ((id >> 3) & 1) {
                // ---- atomic-free CSR fill: 512 edges/block ----
                int e = sub * 512 + (int)threadIdx.x;
                #pragma unroll
                for (int r = 0; r < 2; ++r) {
                    if (e < N_EDGES) {
                        const int d = edst[e];
                        ssorted[coffs[d] + rankv[e]] = esrc[e];
                    }
                    e += 256;
                }
                return;
            }
            role = 0; bx = sub >> 1; by = sub & 1;
            if (bx >= 782) return;
        } else {
            const int lb = id - G0_PAIRS;    // 0..255
            role = 1; bx = lb & 127; by = lb >> 7;
        }
    } else {
        role = blockIdx.z; bx = blockIdx.x; by = blockIdx.y;
        if (role == 1 && bx >= N_LABEL / 64) return;
    }

    const __bf16* Wt = role ? Wt1 : Wt0;
    const float*  bD = role ? bD1 : bD0;
    const float*  bC = role ? bC1 : bC0;

    __shared__ __bf16 As[3 * 64 * 32];    // 12 KB
    __shared__ __bf16 Bs[3 * 128 * 32];   // 24 KB
    __shared__ int s_idx[64];

    const int t    = threadIdx.x;
    const int lane = t & 63;
    const int wave = t >> 6;
    const int m0   = bx * 64;
    const int n0   = by * 128;

    if (role == 1) {
        if (t < 64) s_idx[t] = idx[m0 + t];
        __syncthreads();
    }

    const int arow  = t >> 2;
    const int acol8 = (t & 3) * 8;
    int anode;
    if (role == 1) {
        anode = s_idx[arow];
    } else {
        const int rg = m0 + arow;
        anode = (rg < M) ? rg : (M - 1);   // clamp; stores guarded below
    }
    const __bf16* aptr = A + (size_t)anode * HIDDEN + acol8;

    const __bf16* bptr[2];
    #pragma unroll
    for (int r = 0; r < 2; ++r) {
        const int c = r * 256 + t;
        bptr[r] = Wt + (size_t)(n0 + (c >> 2)) * HIDDEN + (c & 3) * 8;
    }

    f32x4 acc[8];
    #pragma unroll
    for (int i = 0; i < 8; ++i) acc[i] = (f32x4){0.f, 0.f, 0.f, 0.f};

    const int wm   = wave * 16;
    const int fm   = lane & 15;
    const int quad = lane >> 4;

    // ---- depth-2 prefetch pipeline ----
    const __bf16* bp0 = bptr[0];
    const __bf16* bp1 = bptr[1];
    #define STAGE_F(SB, K0)                                                    \
        { load_lds16(aptr + (K0), (void*)(As + (SB) * 2048 + (size_t)t * 8));  \
          load_lds16(bp0 + (K0),  (void*)(Bs + (SB) * 4096 + (size_t)t * 8));  \
          load_lds16(bp1 + (K0),  (void*)(Bs + (SB) * 4096 + (size_t)(256 + t) * 8)); }

    STAGE_F(0, 0)
    STAGE_F(1, 32)
    asm volatile("s_waitcnt vmcnt(3)" ::: "memory");
    __builtin_amdgcn_sched_barrier(0);
    __builtin_amdgcn_s_barrier();

    #pragma unroll
    for (int step = 0; step < NSTEP; ++step) {
        const int cur = step % 3;
        if (step + 2 < NSTEP) {
            const int nb = (step + 2) % 3;
            STAGE_F(nb, (step + 2) * 32)
        }
        const bf16x8 af = *(const bf16x8*)(As + cur * 2048 + (wm + fm) * 32 + quad * 8);
        bf16x8 bfr[8];
        #pragma unroll
        for (int nt = 0; nt < 8; ++nt)
            bfr[nt] = *(const bf16x8*)(Bs + cur * 4096 + (nt * 16 + fm) * 32 + quad * 8);
        #pragma unroll
        for (int nt = 0; nt < 8; ++nt)
            acc[nt] = __builtin_amdgcn_mfma_f32_16x16x32_bf16(
                af, bfr[nt], acc[nt], 0, 0, 0);
        if (step + 2 < NSTEP) asm volatile("s_waitcnt vmcnt(3)" ::: "memory");
        else                  asm volatile("s_waitcnt vmcnt(0)" ::: "memory");
        __builtin_amdgcn_sched_barrier(0);
        __builtin_amdgcn_s_barrier();
    }
    #undef STAGE_F

    // epilogue: C/D layout col=lane&15, row=quad*4+reg (m89/m91-verified)
    float bd[8], bc[8];
    #pragma unroll
    for (int nt = 0; nt < 8; ++nt) {
        const int col = n0 + nt * 16 + fm;
        bd[nt] = DEG_BIAS ? bD[col] : 0.f;
        bc[nt] = bC[col];
    }

    #pragma unroll
    for (int rg = 0; rg < 4; ++rg) {
        const int rloc = wm + quad * 4 + rg;
        int orow;
        if (role == 1) {
            orow = s_idx[rloc];
        } else {
            orow = m0 + rloc;
            if (orow >= M) continue;
            if (flags[orow]) continue;     // labeled: role-1 writes this row
        }
        float bscale = 0.f;
        if constexpr (DEG_BIAS)
            bscale = (float)degv[orow];
        #pragma unroll
        for (int nt = 0; nt < 8; ++nt) {
            const int cb = n0 + nt * 16;       // 16-col group, no 32-boundary cross
            float v = acc[nt][rg];
            if constexpr (DEG_BIAS) v += bscale * bd[nt];
            v += bc[nt];
            Cout[(size_t)(cb >> 5) * SLICE_ELEMS + (size_t)orow * 32
                 + (cb & 31) + fm] = (__bf16)v;
        }
    }
}

// ---------------------------------------------------------------------------
// Plain MFMA GEMM (product batch + final out GEMM), same depth-2 pipeline.
//   GATHER_A   : A-rows gathered via idx (A indexed by node id)
//   DEG_VIA_IDX: A sequential/compact but deg looked up via idx[rloc]
// Row-major in/out (NOT blocked).
// ---------------------------------------------------------------------------
template <bool GATHER_A, bool DEG_BIAS, bool DEG_VIA_IDX, bool OUT_BF16, bool PROD_BATCH>
__global__ __launch_bounds__(256) void mfma_gemm(
    const __bf16* __restrict__ A_in,
    const __bf16* __restrict__ Wt_in,
    const float* __restrict__ biasD,
    void* __restrict__ Cout_in,
    const int* __restrict__ idx,
    const int* __restrict__ degv,
    int M)
{
    const __bf16* A  = A_in;
    const __bf16* Wt = Wt_in;
    void* Cout = Cout_in;
    if constexpr (PROD_BATCH) {
        const int z = blockIdx.z;
        A    = A_in  + (size_t)(3 * (1 + (z >> 1)) + (z & 1)) * WSZ;
        Wt   = Wt_in + (size_t)(z >> 1) * WSZ;
        Cout = (void*)((__bf16*)Cout_in + (size_t)z * WSZ);
    }

    __shared__ __bf16 As[3 * 64 * 32];
    __shared__ __bf16 Bs[3 * 128 * 32];
    __shared__ int s_idx[64];

    const int t    = threadIdx.x;
    const int lane = t & 63;
    const int wave = t >> 6;
    const int m0   = blockIdx.x * 64;
    const int n0   = blockIdx.y * 128;

    if constexpr (GATHER_A || DEG_VIA_IDX) {
        if (t < 64) s_idx[t] = idx[m0 + t];
        __syncthreads();
    }

    const int arow  = t >> 2;
    const int acol8 = (t & 3) * 8;
    int anode;
    if constexpr (GATHER_A) {
        anode = s_idx[arow];
    } else {
        const int rg = m0 + arow;
        anode = (rg < M) ? rg : (M - 1);
    }
    const __bf16* aptr = A + (size_t)anode * HIDDEN + acol8;

    const __bf16* bptr[2];
    #pragma unroll
    for (int r = 0; r < 2; ++r) {
        const int c = r * 256 + t;
        bptr[r] = Wt + (size_t)(n0 + (c >> 2)) * HIDDEN + (c & 3) * 8;
    }

    f32x4 acc[8];
    #pragma unroll
    for (int i = 0; i < 8; ++i) acc[i] = (f32x4){0.f, 0.f, 0.f, 0.f};

    const int wm   = wave * 16;
    const int fm   = lane & 15;
    const int quad = lane >> 4;

    const __bf16* bp0 = bptr[0];
    const __bf16* bp1 = bptr[1];
    #define STAGE_P(SB, K0)                                                    \
        { load_lds16(aptr + (K0), (void*)(As + (SB) * 2048 + (size_t)t * 8));  \
          load_lds16(bp0 + (K0),  (void*)(Bs + (SB) * 4096 + (size_t)t * 8));  \
          load_lds16(bp1 + (K0),  (void*)(Bs + (SB) * 4096 + (size_t)(256 + t) * 8)); }

    STAGE_P(0, 0)
    STAGE_P(1, 32)
    asm volatile("s_waitcnt vmcnt(3)" ::: "memory");
    __builtin_amdgcn_sched_barrier(0);
    __builtin_amdgcn_s_barrier();

    #pragma unroll
    for (int step = 0; step < NSTEP; ++step) {
        const int cur = step % 3;
        if (step + 2 < NSTEP) {
            const int nb = (step + 2) % 3;
            STAGE_P(nb, (step + 2) * 32)
        }
        const bf16x8 af = *(const bf16x8*)(As + cur * 2048 + (wm + fm) * 32 + quad * 8);
        bf16x8 bfr[8];
        #pragma unroll
        for (int nt = 0; nt < 8; ++nt)
            bfr[nt] = *(const bf16x8*)(Bs + cur * 4096 + (nt * 16 + fm) * 32 + quad * 8);
        #pragma unroll
        for (int nt = 0; nt < 8; ++nt)
            acc[nt] = __builtin_amdgcn_mfma_f32_16x16x32_bf16(
                af, bfr[nt], acc[nt], 0, 0, 0);
        if (step + 2 < NSTEP) asm volatile("s_waitcnt vmcnt(3)" ::: "memory");
        else                  asm volatile("s_waitcnt vmcnt(0)" ::: "memory");
        __builtin_amdgcn_sched_barrier(0);
        __builtin_amdgcn_s_barrier();
    }
    #undef STAGE_P

    float bd[8];
    #pragma unroll
    for (int nt = 0; nt < 8; ++nt)
        bd[nt] = DEG_BIAS ? biasD[n0 + nt * 16 + fm] : 0.f;

    #pragma unroll
    for (int rg = 0; rg < 4; ++rg) {
        const int rloc = wm + quad * 4 + rg;
        const int orow = m0 + rloc;
        if (!PROD_BATCH && orow >= M) continue;
        int dnode = orow;
        if constexpr (GATHER_A || DEG_VIA_IDX) dnode = s_idx[rloc];
        float bscale = 0.f;
        if constexpr (DEG_BIAS)
            bscale = (float)degv[dnode];
        #pragma unroll
        for (int nt = 0; nt < 8; ++nt) {
            const int col = n0 + nt * 16 + fm;
            float v = acc[nt][rg];
            if constexpr (DEG_BIAS) v += bscale * bd[nt];
            if constexpr (OUT_BF16)
                ((__bf16*)Cout)[(size_t)orow * HIDDEN + col] = (__bf16)v;
            else
                ((float*)Cout)[(size_t)orow * HIDDEN + col] = v;
        }
    }
}

// ---------------------------------------------------------------------------
// Weight prep + edge histogram + x->bf16 convert, one launch, 159 z-slices:
//  z 0..8  : T[z][n][k] = (bf16)W_z[k][n]  (transpose)
//  z 9..10 : cw_nt straight convert
//  z 11    : qprod
//  z 12..60: edge histogram (rank[e] = returned old count!) + flags +
//            x0b sentinel-row zeroing
//  z 61..158: xb16 = (bf16)x  (feeds GEMM0's uniform gload_lds pipeline)
// ---------------------------------------------------------------------------
__global__ __launch_bounds__(256) void wconv_kernel(
    const float* __restrict__ f0_w, const float* __restrict__ f1_w,
    const float* __restrict__ conv_w, const float* __restrict__ conv_b,
    __bf16* __restrict__ wt_all, __bf16* __restrict__ cw_nt,
    float* __restrict__ q,
    const int* __restrict__ edge_dst, const int* __restrict__ pos,
    int* __restrict__ counts, int* __restrict__ flags,
    int* __restrict__ rankv,
    __bf16* __restrict__ x0b,
    const float* __restrict__ x32, __bf16* __restrict__ xb16)
{
    const int z = blockIdx.z;
    const int tx = threadIdx.x, ty = threadIdx.y;
    const int tt = ty * 32 + tx;

    if (z >= 61) {
        // x -> bf16 conversion (98 planes x 64 blocks x 256 thr x 8 elems)
        const int c = (z - 61) * 64 + blockIdx.x * 8 + blockIdx.y;
        const size_t base = ((size_t)c * 256 + tt) * 8;
        if (base < (size_t)N_NODES * HIDDEN) {
            const float4 u0 = *(const float4*)(x32 + base);
            const float4 u1 = *(const float4*)(x32 + base + 4);
            bf16x8 w = {(__bf16)u0.x, (__bf16)u0.y, (__bf16)u0.z, (__bf16)u0.w,
                        (__bf16)u1.x, (__bf16)u1.y, (__bf16)u1.z, (__bf16)u1.w};
            *(bf16x8*)(xb16 + base) = w;
        }
        return;
    }
    if (z >= 12) {
        const int plane = z - 12;
        const int eb = plane * 64 + blockIdx.x * 8 + blockIdx.y;
        const int e = eb * 256 + tt;
        if (e < N_EDGES) rankv[e] = atomicAdd(&counts[edge_dst[e]], 1);
        if (e < N_LABEL) flags[pos[e]] = 1;   // benign dup writes
        if (plane == 0 && blockIdx.x == 0 && blockIdx.y == 0) {
            const int sl = tt >> 5, c = tt & 31;
            x0b[(size_t)sl * SLICE_ELEMS + (size_t)N_NODES * 32 + c] = (__bf16)0.f;
        }
        return;
    }

    const int kx = blockIdx.x * 32, nx = blockIdx.y * 32;

    if (z < 9) {
        const int layer = z / 3, which = z % 3;
        const float* W = ((which == 0) ? f0_w : (which == 1) ? f1_w : conv_w)
                         + (size_t)layer * WSZ;
        __bf16* T = wt_all + (size_t)z * WSZ;

        __shared__ float tile[32][33];
        for (int i = ty; i < 32; i += 8)
            tile[i][tx] = W[(size_t)(kx + i) * HIDDEN + nx + tx];
        __syncthreads();
        for (int i = ty; i < 32; i += 8)
            T[(size_t)(nx + i) * HIDDEN + kx + tx] = (__bf16)tile[tx][i];
    } else if (z < 11) {
        const int layer = z - 9;
        const float* W = conv_w + (size_t)layer * WSZ;
        __bf16* T = cw_nt + (size_t)layer * WSZ;
        for (int i = ty; i < 32; i += 8)
            T[(size_t)(kx + i) * HIDDEN + nx + tx] =
                (__bf16)W[(size_t)(kx + i) * HIDDEN + nx + tx];
    } else {
        if (blockIdx.x >= 4 || blockIdx.y != 0) return;
        const int zq = blockIdx.x;
        const int l = zq >> 1, branch = zq & 1;
        const float* cb = conv_b + (size_t)l * HIDDEN;
        const float* W  = (branch ? f1_w : f0_w) + (size_t)(l + 1) * WSZ;
        const int n = tt;
        float s = 0.f;
        #pragma unroll 4
        for (int k = 0; k < HIDDEN; ++k)
            s += cb[k] * W[(size_t)k * HIDDEN + n];
        q[(size_t)zq * HIDDEN + n] = s;
    }
}

__device__ __forceinline__ int block_incl_scan(int v, int* s, int t)
{
    s[t] = v; __syncthreads();
    #pragma unroll
    for (int off = 1; off < 256; off <<= 1) {
        int add = (t >= off) ? s[t - off] : 0;
        __syncthreads();
        s[t] += add;
        __syncthreads();
    }
    return s[t];
}

__global__ __launch_bounds__(256) void scan1_kernel(
    const int* __restrict__ counts, int* __restrict__ offs, int* __restrict__ bsum)
{
    __shared__ int s[256];
    const int t = threadIdx.x;
    const int i = blockIdx.x * 256 + t;
    const int pv = (counts[i] + 7) & ~7;       // padded segment length
    int incl = block_incl_scan(pv, s, t);
    offs[i] = incl - pv;
    if (t == 255) bsum[blockIdx.x] = incl;
}

__global__ __launch_bounds__(256) void scan2_kernel(
    const int* __restrict__ bsum, int* __restrict__ bbase)
{
    __shared__ int s[256];
    const int t = threadIdx.x;
    const int v = (t < SCAN_BLOCKS) ? bsum[t] : 0;
    int incl = block_incl_scan(v, s, t);
    bbase[t] = incl - v;
}

__global__ __launch_bounds__(256) void scan3_kernel(
    int* __restrict__ offs, const int* __restrict__ bbase,
    const int* __restrict__ counts, int* __restrict__ src_sorted)
{
    const int i = blockIdx.x * 256 + threadIdx.x;
    const int o = offs[i] + bbase[blockIdx.x];
    offs[i] = o;
    // fill the padding tail of this segment with the zero-row sentinel
    const int v  = counts[i];
    const int pv = (v + 7) & ~7;
    for (int j = o + v; j < o + pv; ++j) src_sorted[j] = N_NODES;
}

// ---------------------------------------------------------------------------
// XCD-sliced pull-mode segment sum, branch-free window-8 (R15).
// slice = blockIdx.x & 7 pins each 3.2MB column slice to one XCD L2.
// ---------------------------------------------------------------------------
template <bool COMPACT>
__global__ __launch_bounds__(256) void seg_slice_kernel(
    const __bf16* __restrict__ x0b,
    const int* __restrict__ srcs,
    const int* __restrict__ offs,      // PADDED offsets (multiples of 8)
    const int* __restrict__ nodelist,
    __bf16* __restrict__ out)
{
    const int slice = blockIdx.x & 7;
    const int chunk = blockIdx.x >> 3;
    const int t    = threadIdx.x;
    const int wave = t >> 6;
    const int lane = t & 63;
    const int g    = lane >> 2;      // 16 groups per wave
    const int li   = lane & 3;       // 4 lanes per dst row, 8 cols each
    const int rw   = chunk * 64 + wave * 16 + g;
    if (!COMPACT && rw >= N_NODES) return;

    const int d    = COMPACT ? nodelist[rw] : rw;
    const int beg  = offs[d];
    const int pdeg = offs[d + 1] - beg;   // multiple of 8

    const char* xb = (const char*)(x0b + (size_t)slice * SLICE_ELEMS);
    const uint32_t lioff = (uint32_t)li * 16u;
    const int* sp = srcs + beg;           // 32B-aligned

    f32x2 a[4];
    #pragma unroll
    for (int j = 0; j < 4; ++j) a[j] = (f32x2){0.f, 0.f};

    int4 j0, j1;
    if (pdeg > 0) {
        j0 = *(const int4*)(sp);
        j1 = *(const int4*)(sp + 4);
    }

    for (int base = 0; base < pdeg; base += 8) {
        const int4 k0 = j0, k1 = j1;
        if (base + 8 < pdeg) {            // prefetch next window's indices
            j0 = *(const int4*)(sp + base + 8);
            j1 = *(const int4*)(sp + base + 12);
        }
        const uint4 c0 = *(const uint4*)(xb + (((uint32_t)k0.x << 6) + lioff));
        const uint4 c1 = *(const uint4*)(xb + (((uint32_t)k0.y << 6) + lioff));
        const uint4 c2 = *(const uint4*)(xb + (((uint32_t)k0.z << 6) + lioff));
        const uint4 c3 = *(const uint4*)(xb + (((uint32_t)k0.w << 6) + lioff));
        const uint4 c4 = *(const uint4*)(xb + (((uint32_t)k1.x << 6) + lioff));
        const uint4 c5 = *(const uint4*)(xb + (((uint32_t)k1.y << 6) + lioff));
        const uint4 c6 = *(const uint4*)(xb + (((uint32_t)k1.z << 6) + lioff));
        const uint4 c7 = *(const uint4*)(xb + (((uint32_t)k1.w << 6) + lioff));
        acc8(c0, a); acc8(c1, a); acc8(c2, a); acc8(c3, a);
        acc8(c4, a); acc8(c5, a); acc8(c6, a); acc8(c7, a);
    }

    bf16x8 o;
    #pragma unroll
    for (int j = 0; j < 4; ++j) {
        o[2 * j]     = (__bf16)a[j].x;
        o[2 * j + 1] = (__bf16)a[j].y;
    }
    *(bf16x8*)(out + (size_t)rw * HIDDEN + (slice << 5) + li * 8) = o;
}

extern "C" void kernel_launch(void* const* d_in, const int* in_sizes, int n_in,
                              void* d_out, int out_size, void* d_ws, size_t ws_size,
                              hipStream_t stream)
{
    const float* x       = (const float*)d_in[0];
    const float* f0_w    = (const float*)d_in[1];
    const float* f0_b    = (const float*)d_in[2];
    const float* f1_w    = (const float*)d_in[3];
    const float* f1_b    = (const float*)d_in[4];
    const float* conv_w  = (const float*)d_in[5];
    const float* conv_b  = (const float*)d_in[6];
    const int*   edge_src = (const int*)d_in[7];
    const int*   edge_dst = (const int*)d_in[8];
    const int*   pos      = (const int*)d_in[9];
    float* out = (float*)d_out;

    const size_t buf = (size_t)N_NODES * HIDDEN;   // 12.8M elems

    char* p = (char*)d_ws;
    __bf16* bufA   = (__bf16*)p; p += buf * 2;                 // 25.6 MB (xb16 / S)
    __bf16* bufB   = (__bf16*)p; p += SLICE_ELEMS * 8 * 2;     // 25.6 MB+ (blocked x0)
    __bf16* s_lbl  = (__bf16*)p; p += (size_t)N_LABEL * HIDDEN * 2;  // 4 MB
    __bf16* wt_all = (__bf16*)p; p += (size_t)9 * WSZ * 2;
    __bf16* prod   = (__bf16*)p; p += (size_t)4 * WSZ * 2;
    __bf16* cw_nt  = (__bf16*)p; p += (size_t)2 * WSZ * 2;
    float*  qv     = (float*)p;  p += (size_t)4 * HIDDEN * 4;
    int* counts     = (int*)p;  p += NPAD * 4;     // true degree (kept live!)
    int* flags      = (int*)p;  p += NPAD * 4;     // labeled-row bitmap
    int* offs       = (int*)p;  p += NPAD * 4;     // PADDED offsets
    int* bsum       = (int*)p;  p += 256 * 4;
    int* bbase      = (int*)p;  p += 256 * 4;
    int* rankv      = (int*)p;  p += (size_t)N_EDGES * 4;      // 3.2 MB
    int* src_sorted = (int*)p;  p += (size_t)(N_EDGES + 7 * NPAD) * 4;

    // ---- CSR stage 1: histogram(+rank)+flags + x->bf16 fused into prep ----
    hipMemsetAsync(counts, 0, 2 * NPAD * sizeof(int), stream);
    wconv_kernel<<<dim3(8, 8, 159), dim3(32, 8), 0, stream>>>(
        f0_w, f1_w, conv_w, conv_b, wt_all, cw_nt, qv,
        edge_dst, pos, counts, flags, rankv, bufB, x, bufA);
    scan1_kernel<<<SCAN_BLOCKS, 256, 0, stream>>>(counts, offs, bsum);
    scan2_kernel<<<1, 256, 0, stream>>>(bsum, bbase);
    scan3_kernel<<<SCAN_BLOCKS, 256, 0, stream>>>(offs, bbase, counts, src_sorted);

    // all 4 products prod_t[z] = (Cw_l · F_{l+1})^T in ONE batched launch
    mfma_gemm<false, false, false, true, true><<<dim3(4, 2, 4), 256, 0, stream>>>(
        wt_all, cw_nt, nullptr, prod, nullptr, nullptr, HIDDEN);

    const dim3 fused_grid(782, 2, 2);   // z=0 full, z=1 label (layers 1..)
    const dim3 lbl_grid(128, 2);

    __bf16* cur = bufA;              // S buffer (= xb16 at layer 0)
    __bf16* tmp = bufB;              // x0 buffer, COLUMN-BLOCKED layout

    for (int l = 0; l < N_LAYERS; ++l) {
        const float* B0 = f0_b + (size_t)l * HIDDEN;
        const float* B1 = f1_b + (size_t)l * HIDDEN;

        if (l == 0) {
            // x0 = xb16@F0_0+b0 (all, minus labeled) ∪ xb16@F1_0+b1 (labeled)
            // + atomic-free CSR fill blocks INTERLEAVED in groups of 8
            mfma_gemm_fused<false, true><<<G0_TOTAL, 256, 0, stream>>>(
                bufA, wt_all + 0 * WSZ, wt_all + 1 * WSZ,
                nullptr, nullptr, B0, B1, tmp, pos, counts, flags,
                edge_src, edge_dst, offs, rankv, src_sorted, N_NODES);
        } else {
            // x0 = S@(Cw·F0_l)+deg*q0+b0 ∪ S@(Cw·F1_l)+deg*q1+b1 (folded conv)
            const int z0 = (l - 1) * 2;
            mfma_gemm_fused<true, false><<<fused_grid, 256, 0, stream>>>(
                cur, prod + (size_t)z0 * WSZ, prod + (size_t)(z0 + 1) * WSZ,
                qv + (size_t)z0 * HIDDEN, qv + (size_t)(z0 + 1) * HIDDEN,
                B0, B1, tmp, pos, counts, flags,
                nullptr, nullptr, nullptr, nullptr, nullptr, N_NODES);
        }

        if (l < N_LAYERS - 1) {
            // S = segment_sum(x0[src]) at ALL nodes (tmp -> cur), XCD-sliced
            seg_slice_kernel<false><<<8 * SEG_CHUNKS, 256, 0, stream>>>(
                tmp, src_sorted, offs, nullptr, cur);
        } else {
            // S only at labeled dst nodes (tmp -> s_lbl, compact pos order)
            seg_slice_kernel<true><<<8 * (N_LABEL / 64), 256, 0, stream>>>(
                tmp, src_sorted, offs, pos, s_lbl);
            // out[i] = S_lbl[i] @ Cw_2 + deg[pos[i]]*cb_2  -> d_out (fp32)
            mfma_gemm<false, true, true, false, false><<<lbl_grid, 256, 0, stream>>>(
                s_lbl, wt_all + (size_t)(2 * 3 + 2) * WSZ,
                conv_b + (size_t)2 * HIDDEN, out, pos, counts, N_LABEL);
        }
    }
}